// Round 4
// baseline (18482.416 us; speedup 1.0000x reference)
//
#include <hip/hip_runtime.h>

// T=32 enc + 32 dec, B=64, N=64, H=128, Din=Dout=1.
// One persistent block per batch: 64 blocks x 1024 threads (16 waves, 4/SIMD).
// Lane = node (64 lanes = 64 nodes); wave w owns feature columns [8w, 8w+8).
// Weights are read as lane-invariant global loads (no duplication across rows).
// All [64][128] LDS state buffers use a 4-float XOR swizzle -> conflict-free b128.

#define O_H0   0        // [64][128] swizzled, layer-0 state
#define O_H1   8192     // [64][128] swizzled, layer-1 state
#define O_RH   16384    // [64][128] swizzled, r*h
#define O_MT   24576    // [128][64]  Mt[f][n] = (S@src)^T  (conflict-free by layout)
#define O_STB  32768    // [64][64]   stb[m][n] = S[b][n][m]
#define O_XS   36864    // [64] sparse x
#define O_MP   36928    // [16][64] proj partials
#define LDS_FLOATS 37952
#define LDS_BYTES (LDS_FLOATS * 4)   // 151808 <= 160 KiB

struct KParams {
  const float* inp;   // [32,64,64]
  const float* S;     // [64,64,64]
  const float* w[16]; // e0{Wru,bru,Wc,bc} e1{..} d0{..} db{..}
  const float* Wp;    // [128]
  const float* bp;    // [1]
  float* out;         // [32,64,64]
};

__device__ __forceinline__ float sigm(float v) { return 1.f / (1.f + __expf(-v)); }

// swizzled float index of (row n, col f0), f0 % 4 == 0, for [64][128] buffers
__device__ __forceinline__ int sidx(int n, int f0) {
  return n * 128 + ((((f0 >> 2) ^ (n & 31)) & 31) << 2);
}

// MT[f][n] = sum_m src[m][f] * stb[m][n]  for this wave's f-slice [f0, f0+8)
__device__ __forceinline__ void mixt(float* __restrict__ L, const float* __restrict__ src,
                                     int lane, int f0)
{
  const float* stb = L + O_STB;
  float acc[8] = {0.f, 0.f, 0.f, 0.f, 0.f, 0.f, 0.f, 0.f};
  const int g0 = f0 >> 2;
  #pragma unroll 4
  for (int m = 0; m < 64; ++m) {
    const float sv = stb[m * 64 + lane];                               // lane-varying, contiguous
    const float4 a = *(const float4*)&src[m * 128 + (((g0 ^ (m & 31)) & 31) << 2)];       // uniform
    const float4 b = *(const float4*)&src[m * 128 + ((((g0 + 1) ^ (m & 31)) & 31) << 2)]; // uniform
    acc[0] += a.x * sv; acc[1] += a.y * sv; acc[2] += a.z * sv; acc[3] += a.w * sv;
    acc[4] += b.x * sv; acc[5] += b.y * sv; acc[6] += b.z * sv; acc[7] += b.w * sv;
  }
  float* MT = L + O_MT;
  #pragma unroll
  for (int j = 0; j < 8; ++j) MT[(f0 + j) * 64 + lane] = acc[j];       // contiguous, no conflict
}

#define FMA8(ACC, V0, V1) \
  ACC[0] += p * V0.x; ACC[1] += p * V0.y; ACC[2] += p * V0.z; ACC[3] += p * V0.w; \
  ACC[4] += p * V1.x; ACC[5] += p * V1.y; ACC[6] += p * V1.z; ACC[7] += p * V1.w;

// k=128: r,u,c together (dense x-part). wr -> Wru rows, wc -> Wc rows (pre-offset to f0)
__device__ __forceinline__ void accum_ruc(const float* __restrict__ MT,
    const float* __restrict__ wr, const float* __restrict__ wc,
    float racc[8], float uacc[8], float cacc[8], int lane)
{
  #pragma unroll 4
  for (int kk = 0; kk < 128; ++kk) {
    const float p = MT[kk * 64 + lane];
    const float4 r0 = *(const float4*)&wr[kk * 256];
    const float4 r1 = *(const float4*)&wr[kk * 256 + 4];
    const float4 u0 = *(const float4*)&wr[kk * 256 + 128];
    const float4 u1 = *(const float4*)&wr[kk * 256 + 132];
    const float4 c0 = *(const float4*)&wc[kk * 128];
    const float4 c1 = *(const float4*)&wc[kk * 128 + 4];
    FMA8(racc, r0, r1)
    FMA8(uacc, u0, u1)
    FMA8(cacc, c0, c1)
  }
}

__device__ __forceinline__ void accum_ru(const float* __restrict__ MT,
    const float* __restrict__ wr, float racc[8], float uacc[8], int lane)
{
  #pragma unroll 4
  for (int kk = 0; kk < 128; ++kk) {
    const float p = MT[kk * 64 + lane];
    const float4 r0 = *(const float4*)&wr[kk * 256];
    const float4 r1 = *(const float4*)&wr[kk * 256 + 4];
    const float4 u0 = *(const float4*)&wr[kk * 256 + 128];
    const float4 u1 = *(const float4*)&wr[kk * 256 + 132];
    FMA8(racc, r0, r1)
    FMA8(uacc, u0, u1)
  }
}

__device__ __forceinline__ void accum_c(const float* __restrict__ MT,
    const float* __restrict__ wc, float cacc[8], int lane)
{
  #pragma unroll 4
  for (int kk = 0; kk < 128; ++kk) {
    const float p = MT[kk * 64 + lane];
    const float4 c0 = *(const float4*)&wc[kk * 128];
    const float4 c1 = *(const float4*)&wc[kk * 128 + 4];
    FMA8(cacc, c0, c1)
  }
}

// gates -> rh -> mix(rh) -> c-accum -> h update. H = state buffer being updated.
__device__ __forceinline__ void cell_tail(float* __restrict__ L, float* __restrict__ H,
    const float* __restrict__ wc_h, const float* __restrict__ bru, const float* __restrict__ bc,
    float racc[8], float uacc[8], float cacc[8], int lane, int f0)
{
  float rr[8], uu[8];
  #pragma unroll
  for (int j = 0; j < 8; ++j) {
    rr[j] = sigm(racc[j] + bru[f0 + j]);
    uu[j] = sigm(uacc[j] + bru[128 + f0 + j]);
  }
  float* RH = L + O_RH;
  const int i0 = sidx(lane, f0), i1 = sidx(lane, f0 + 4);
  float4 h0 = *(float4*)&H[i0], h1 = *(float4*)&H[i1];
  *(float4*)&RH[i0] = make_float4(rr[0] * h0.x, rr[1] * h0.y, rr[2] * h0.z, rr[3] * h0.w);
  *(float4*)&RH[i1] = make_float4(rr[4] * h1.x, rr[5] * h1.y, rr[6] * h1.z, rr[7] * h1.w);
  __syncthreads();                 // RH visible; MT free (accum done everywhere)
  mixt(L, L + O_RH, lane, f0);
  __syncthreads();                 // MT = (S@rh)^T ready
  accum_c(L + O_MT, wc_h, cacc, lane);
  float cv[8];
  #pragma unroll
  for (int j = 0; j < 8; ++j) cv[j] = tanhf(cacc[j] + bc[f0 + j]);
  h0.x = uu[0] * h0.x + (1.f - uu[0]) * cv[0];
  h0.y = uu[1] * h0.y + (1.f - uu[1]) * cv[1];
  h0.z = uu[2] * h0.z + (1.f - uu[2]) * cv[2];
  h0.w = uu[3] * h0.w + (1.f - uu[3]) * cv[3];
  h1.x = uu[4] * h1.x + (1.f - uu[4]) * cv[4];
  h1.y = uu[5] * h1.y + (1.f - uu[5]) * cv[5];
  h1.z = uu[6] * h1.z + (1.f - uu[6]) * cv[6];
  h1.w = uu[7] * h1.w + (1.f - uu[7]) * cv[7];
  *(float4*)&H[i0] = h0;
  *(float4*)&H[i1] = h1;
  __syncthreads();                 // state ready for next cell
}

// Din=128 cell: x = H0 (LDS), h = H1 (LDS)
__device__ __forceinline__ void cell_dense(float* __restrict__ L, int lane, int f0,
    const float* __restrict__ Wru, const float* __restrict__ bru,
    const float* __restrict__ Wc, const float* __restrict__ bc)
{
  mixt(L, L + O_H0, lane, f0);     // MT = (S@x)^T
  __syncthreads();
  float racc[8] = {0.f}, uacc[8] = {0.f}, cacc[8] = {0.f};
  accum_ruc(L + O_MT, Wru + f0, Wc + f0, racc, uacc, cacc, lane);    // x-rows 0..127
  __syncthreads();                 // MT free
  mixt(L, L + O_H1, lane, f0);     // MT = (S@h)^T
  __syncthreads();
  accum_ru(L + O_MT, Wru + 128 * 256 + f0, racc, uacc, lane);        // h-rows 128..255
  cell_tail(L, L + O_H1, Wc + 128 * 128 + f0, bru, bc, racc, uacc, cacc, lane, f0);
}

// Din=1 cell: h = H0 (LDS); x in XS (or absent)
__device__ __forceinline__ void cell_sparse(float* __restrict__ L, int lane, int f0, bool hasx,
    const float* __restrict__ Wru, const float* __restrict__ bru,
    const float* __restrict__ Wc, const float* __restrict__ bc)
{
  mixt(L, L + O_H0, lane, f0);     // MT = (S@h)^T
  __syncthreads();
  float racc[8] = {0.f}, uacc[8] = {0.f}, cacc[8] = {0.f};
  accum_ru(L + O_MT, Wru + 256 + f0, racc, uacc, lane);              // h-rows 1..128
  if (hasx) {
    const float* stb = L + O_STB;
    const float* XS = L + O_XS;
    float mxv = 0.f;               // (S@x)[lane]
    #pragma unroll 4
    for (int m = 0; m < 64; m += 4) {
      const float4 x4 = *(const float4*)&XS[m];
      mxv += stb[(m + 0) * 64 + lane] * x4.x + stb[(m + 1) * 64 + lane] * x4.y
           + stb[(m + 2) * 64 + lane] * x4.z + stb[(m + 3) * 64 + lane] * x4.w;
    }
    #pragma unroll
    for (int j = 0; j < 8; ++j) {   // rank-1 x contribution, W row 0
      racc[j] += mxv * Wru[f0 + j];
      uacc[j] += mxv * Wru[128 + f0 + j];
      cacc[j] += mxv * Wc[f0 + j];
    }
  }
  cell_tail(L, L + O_H0, Wc + 128 + f0, bru, bc, racc, uacc, cacc, lane, f0);
}

__device__ __forceinline__ void proj(float* __restrict__ L, int lane, int f0,
    const float* __restrict__ Wp, const float* __restrict__ bp, float* __restrict__ outg)
{
  const float* H = L + O_H1;
  const int i0 = sidx(lane, f0), i1 = sidx(lane, f0 + 4);
  const float4 h0 = *(const float4*)&H[i0], h1 = *(const float4*)&H[i1];
  const float4 w0 = *(const float4*)&Wp[f0], w1 = *(const float4*)&Wp[f0 + 4];
  (L + O_MP)[(f0 >> 3) * 64 + lane] =
      h0.x * w0.x + h0.y * w0.y + h0.z * w0.z + h0.w * w0.w +
      h1.x * w1.x + h1.y * w1.y + h1.z * w1.z + h1.w * w1.w;
  __syncthreads();
  if (threadIdx.x < 64) {
    const float* MP = L + O_MP;
    float v = bp[0];
    #pragma unroll
    for (int w2 = 0; w2 < 16; ++w2) v += MP[w2 * 64 + lane];
    outg[lane] = v;
    (L + O_XS)[lane] = v;          // decoder feedback
  }
  __syncthreads();
}

__global__ __launch_bounds__(1024, 4) void gcgru_persist(KParams p)
{
  extern __shared__ float L[];
  const int tid = threadIdx.x, b = blockIdx.x;
  const int lane = tid & 63;
  const int f0 = (tid >> 6) * 8;   // wave's column slice

  for (int i = tid; i < 16384; i += 1024) L[i] = 0.f;   // zero H0, H1
  const float* Sb = p.S + (size_t)b * 4096;
  for (int i = tid; i < 4096; i += 1024)
    (L + O_STB)[i] = Sb[(i & 63) * 64 + (i >> 6)];      // stb[m][n] = S[n][m]
  __syncthreads();

  for (int t = 0; t < 32; ++t) {
    if (tid < 64) (L + O_XS)[tid] = p.inp[((size_t)t * 64 + b) * 64 + tid];
    cell_sparse(L, lane, f0, true, p.w[0], p.w[1], p.w[2], p.w[3]);
    cell_dense (L, lane, f0,       p.w[4], p.w[5], p.w[6], p.w[7]);
  }
  for (int t = 0; t < 32; ++t) {
    cell_sparse(L, lane, f0, t > 0, p.w[8],  p.w[9],  p.w[10], p.w[11]);
    cell_dense (L, lane, f0,        p.w[12], p.w[13], p.w[14], p.w[15]);
    proj(L, lane, f0, p.Wp, p.bp, p.out + (size_t)t * 4096 + (size_t)b * 64);
  }
}

extern "C" void kernel_launch(void* const* d_in, const int* in_sizes, int n_in,
                              void* d_out, int out_size, void* d_ws, size_t ws_size,
                              hipStream_t stream)
{
  KParams p;
  p.inp = (const float*)d_in[0];
  p.S   = (const float*)d_in[2];
  for (int i = 0; i < 16; ++i) p.w[i] = (const float*)d_in[3 + i];
  p.Wp = (const float*)d_in[19];
  p.bp = (const float*)d_in[20];
  p.out = (float*)d_out;

  (void)hipFuncSetAttribute((const void*)gcgru_persist,
                            hipFuncAttributeMaxDynamicSharedMemorySize, LDS_BYTES);
  gcgru_persist<<<dim3(64), dim3(1024), LDS_BYTES, stream>>>(p);
}

// Round 6
// 13284.825 us; speedup vs baseline: 1.3912x; 1.3912x over previous
//
#include <hip/hip_runtime.h>

// T=32 enc + 32 dec, B=64, N=64, H=128, Din=Dout=1.
// 256 blocks (4 per batch, feature-sliced 32 cols each) x 1024 threads.
// Cooperative launch; per-batch global barrier; Mt exchanged via L2/L3.

#define NN 64
#define NH 128
#define FS 32
#define PARTS 4
#define NTH 1024

typedef float f4v __attribute__((ext_vector_type(4)));

// LDS layout (floats)
#define L_H0   0        // [64][32] my feature-slice of layer-0 state
#define L_H1   2048     // [64][32] layer-1 state slice
#define L_RH   4096     // [64][32] r*h slice
#define L_STB  6144     // [64][64] stb[m][n] = S[b][n][m]
#define L_MT   10240    // [256][64] staged Mt (all parts)
#define L_XS   26624    // [64] sparse x
#define L_SX   26688    // [64] S@x
#define L_RED  26752    // [64][17] proj partials
#define LDSF   27840
#define LDS_BYTES (LDSF * 4)   // 111360 B

struct KP {
  const float* inp; const float* S;
  const float* w[16];   // e0{Wru,bru,Wc,bc} e1{..} d0{..} db{..}
  const float* Wp; const float* bp;
  float* out;
  float* mtg;           // ws: [64 batches][384][64] Mt exchange
  float* pp;            // ws: [64][4][64] proj partials
  unsigned* bar;        // ws: [64][16] {ctr, gen} per batch
};

__device__ __forceinline__ float sigm(float v) { return 1.f / (1.f + __expf(-v)); }

// per-batch barrier: release fence -> arrive -> spin on generation -> acquire fence
__device__ __forceinline__ void xbar(unsigned* ctr, int tid)
{
  __syncthreads();                       // all block stores issued & drained
  if (tid == 0) {
    __threadfence();                     // release: make Mt visible device-wide
    unsigned* gen = ctr + 1;
    unsigned g = __hip_atomic_load(gen, __ATOMIC_RELAXED, __HIP_MEMORY_SCOPE_AGENT);
    unsigned old = __hip_atomic_fetch_add(ctr, 1u, __ATOMIC_ACQ_REL, __HIP_MEMORY_SCOPE_AGENT);
    if (old == PARTS - 1) {
      __hip_atomic_store(ctr, 0u, __ATOMIC_RELAXED, __HIP_MEMORY_SCOPE_AGENT);
      __hip_atomic_store(gen, g + 1u, __ATOMIC_RELEASE, __HIP_MEMORY_SCOPE_AGENT);
    } else {
      while (__hip_atomic_load(gen, __ATOMIC_RELAXED, __HIP_MEMORY_SCOPE_AGENT) == g)
        __builtin_amdgcn_s_sleep(8);
    }
    __threadfence();                     // acquire: don't read stale Mt
  }
  __syncthreads();
}

// Mt rows [cb+2wv, cb+2wv+1] <- (S @ src)^T for my feature pair. src local [64][32].
__device__ __forceinline__ void mix_slice(const float* L, int srcOff, float* mtg_rows,
                                          int lane, int wv)
{
  const float* src = L + srcOff;
  const float* stb = L + L_STB;
  const int f = wv * 2;
  float a0 = 0.f, a1 = 0.f;
  #pragma unroll 8
  for (int m = 0; m < 64; ++m) {
    const float s = stb[m * 64 + lane];                 // lane-varying b32, conflict-free
    const float2 x2 = *(const float2*)&src[m * 32 + f]; // wave-uniform b64 broadcast
    a0 += x2.x * s; a1 += x2.y * s;
  }
  __builtin_nontemporal_store(a0, &mtg_rows[f * 64 + lane]);
  __builtin_nontemporal_store(a1, &mtg_rows[(f + 1) * 64 + lane]);
}

__device__ __forceinline__ void stage(float* L, const float* mtg, int rowBase, int nfloats, int tid)
{
  const f4v* g = (const f4v*)(mtg + rowBase * 64);
  f4v* d = (f4v*)(L + L_MT);
  const int nv = nfloats >> 2;
  for (int i = tid; i < nv; i += NTH) d[i] = __builtin_nontemporal_load(&g[i]);
}

// gates -> rh -> mix(rh) -> exchange -> c-gemm -> h update
__device__ __forceinline__ void cell_tail(float* L, float* mtg, unsigned* ctr,
    const float* wc_h, const float* bru, const float* bc,
    float2 ra, float2 ua, float2 ca, int hOff,
    int tid, int lane, int wv, int cb)
{
  const int n = tid >> 4, c2 = (tid & 15) * 2, cg = cb + c2;
  const float2 b1 = *(const float2*)&bru[cg];
  const float2 b2 = *(const float2*)&bru[NH + cg];
  const float r0 = sigm(ra.x + b1.x), r1 = sigm(ra.y + b1.y);
  const float u0 = sigm(ua.x + b2.x), u1 = sigm(ua.y + b2.y);
  float* H = L + hOff;
  float2 h2 = *(float2*)&H[n * FS + c2];
  *(float2*)&L[L_RH + n * FS + c2] = make_float2(r0 * h2.x, r1 * h2.y);
  __syncthreads();
  mix_slice(L, L_RH, mtg + (256 + cb) * 64, lane, wv);   // rows 256..383
  xbar(ctr, tid);
  stage(L, mtg, 256, 128 * 64, tid);
  __syncthreads();
  const float* MtL = L + L_MT;
  #pragma unroll 4
  for (int k = 0; k < 128; ++k) {
    const float pv = MtL[k * 64 + n];
    const float2 wc2 = *(const float2*)&wc_h[k * NH];
    ca.x += pv * wc2.x; ca.y += pv * wc2.y;
  }
  const float2 b3 = *(const float2*)&bc[cg];
  const float c0 = tanhf(ca.x + b3.x), c1 = tanhf(ca.y + b3.y);
  h2.x = u0 * h2.x + (1.f - u0) * c0;
  h2.y = u1 * h2.y + (1.f - u1) * c1;
  *(float2*)&H[n * FS + c2] = h2;
  __syncthreads();
}

// Din=128 cell: x = H0 slice, h = H1 slice
__device__ __forceinline__ void cell_dense(float* L, float* mtg, unsigned* ctr,
    const float* Wru, const float* bru, const float* Wc, const float* bc,
    int tid, int lane, int wv, int cb)
{
  mix_slice(L, L_H0, mtg + cb * 64, lane, wv);           // rows 0..127
  mix_slice(L, L_H1, mtg + (128 + cb) * 64, lane, wv);   // rows 128..255
  xbar(ctr, tid);
  stage(L, mtg, 0, 256 * 64, tid);
  __syncthreads();
  const int n = tid >> 4, c2 = (tid & 15) * 2, cg = cb + c2;
  float2 ra = make_float2(0.f, 0.f), ua = ra, ca = ra;
  const float* MtL = L + L_MT;
  {
    const float* w1 = Wru + cg;                          // x-rows 0..127
    const float* w2 = Wc + cg;
    #pragma unroll 4
    for (int k = 0; k < 128; ++k) {
      const float pv = MtL[k * 64 + n];
      const float2 wr = *(const float2*)&w1[k * 256];
      const float2 wu = *(const float2*)&w1[k * 256 + NH];
      const float2 wc2 = *(const float2*)&w2[k * NH];
      ra.x += pv * wr.x; ra.y += pv * wr.y;
      ua.x += pv * wu.x; ua.y += pv * wu.y;
      ca.x += pv * wc2.x; ca.y += pv * wc2.y;
    }
  }
  {
    const float* w1 = Wru + 128 * 256 + cg;              // h-rows 128..255
    #pragma unroll 4
    for (int k = 0; k < 128; ++k) {
      const float pv = MtL[(128 + k) * 64 + n];
      const float2 wr = *(const float2*)&w1[k * 256];
      const float2 wu = *(const float2*)&w1[k * 256 + NH];
      ra.x += pv * wr.x; ra.y += pv * wr.y;
      ua.x += pv * wu.x; ua.y += pv * wu.y;
    }
  }
  cell_tail(L, mtg, ctr, Wc + 128 * NH + cg, bru, bc, ra, ua, ca, L_H1, tid, lane, wv, cb);
}

// Din=1 cell: h = H0 slice; x in XS (rank-1 via S@x)
__device__ __forceinline__ void cell_sparse(float* L, float* mtg, unsigned* ctr,
    const float* Wru, const float* bru, const float* Wc, const float* bc,
    bool hasx, int tid, int lane, int wv, int cb)
{
  mix_slice(L, L_H0, mtg + cb * 64, lane, wv);           // rows 0..127
  xbar(ctr, tid);
  stage(L, mtg, 0, 128 * 64, tid);
  if (hasx && wv == 0) {                                 // Sx[n] = (S@x)[n]
    const float* stb = L + L_STB; const float* xs = L + L_XS;
    float s = 0.f;
    #pragma unroll 8
    for (int m = 0; m < 64; ++m) s += stb[m * 64 + lane] * xs[m];
    L[L_SX + lane] = s;
  }
  __syncthreads();
  const int n = tid >> 4, c2 = (tid & 15) * 2, cg = cb + c2;
  float2 ra = make_float2(0.f, 0.f), ua = ra, ca = ra;
  const float* MtL = L + L_MT;
  {
    const float* w1 = Wru + 256 + cg;                    // h-rows 1..128
    #pragma unroll 4
    for (int k = 0; k < 128; ++k) {
      const float pv = MtL[k * 64 + n];
      const float2 wr = *(const float2*)&w1[k * 256];
      const float2 wu = *(const float2*)&w1[k * 256 + NH];
      ra.x += pv * wr.x; ra.y += pv * wr.y;
      ua.x += pv * wu.x; ua.y += pv * wu.y;
    }
  }
  if (hasx) {                                            // rank-1 x term, W row 0
    const float sx = L[L_SX + n];
    const float2 w0r = *(const float2*)&Wru[cg];
    const float2 w0u = *(const float2*)&Wru[NH + cg];
    const float2 w0c = *(const float2*)&Wc[cg];
    ra.x += sx * w0r.x; ra.y += sx * w0r.y;
    ua.x += sx * w0u.x; ua.y += sx * w0u.y;
    ca.x += sx * w0c.x; ca.y += sx * w0c.y;
  }
  cell_tail(L, mtg, ctr, Wc + NH + cg, bru, bc, ra, ua, ca, L_H0, tid, lane, wv, cb);
}

__device__ __forceinline__ void proj_step(float* L, float* ppb, unsigned* ctr,
    const float* Wp, const float* bp, float* outp, int tid, int part, int cb)
{
  const int n = tid >> 4, fq = tid & 15, f2 = fq * 2;
  const float2 h2 = *(const float2*)&L[L_H1 + n * FS + f2];
  const float2 w2 = *(const float2*)&Wp[cb + f2];
  L[L_RED + n * 17 + fq] = h2.x * w2.x + h2.y * w2.y;
  __syncthreads();
  if (tid < 64) {
    float s = 0.f;
    #pragma unroll
    for (int q = 0; q < 16; ++q) s += L[L_RED + tid * 17 + q];
    if (part == 0) s += bp[0];
    ppb[part * 64 + tid] = s;
  }
  xbar(ctr, tid);
  if (tid < 64) {
    const float s = ppb[tid] + ppb[64 + tid] + ppb[128 + tid] + ppb[192 + tid];
    L[L_XS + tid] = s;                                   // decoder feedback
    if (part == 0) outp[tid] = s;
  }
  __syncthreads();
}

__global__ __launch_bounds__(NTH, 1) void gcgru_coop(KP p)
{
  extern __shared__ float L[];
  const int tid = threadIdx.x, bid = blockIdx.x;
  const int xcd = bid & 7, slot = bid >> 3;              // keep a batch's 4 parts on one XCD
  const int batch = (slot >> 2) * 8 + xcd;
  const int part = slot & 3;
  const int lane = tid & 63, wv = tid >> 6;
  const int cb = part * FS;
  float* mtg = p.mtg + (size_t)batch * (384 * 64);
  float* ppb = p.pp + (size_t)batch * 256;
  unsigned* ctr = p.bar + batch * 16;

  for (int i = tid; i < 4096; i += NTH) L[i] = 0.f;      // zero H0, H1 slices
  const float* Sb = p.S + (size_t)batch * 4096;
  for (int i = tid; i < 4096; i += NTH)
    L[L_STB + i] = Sb[(i & 63) * 64 + (i >> 6)];         // stb[m][n] = S[n][m]
  __syncthreads();

  for (int t = 0; t < 32; ++t) {
    if (tid < 64) L[L_XS + tid] = p.inp[((size_t)t * 64 + batch) * 64 + tid];
    cell_sparse(L, mtg, ctr, p.w[0], p.w[1], p.w[2], p.w[3], true, tid, lane, wv, cb);
    cell_dense (L, mtg, ctr, p.w[4], p.w[5], p.w[6], p.w[7], tid, lane, wv, cb);
  }
  for (int t = 0; t < 32; ++t) {
    cell_sparse(L, mtg, ctr, p.w[8], p.w[9], p.w[10], p.w[11], t > 0, tid, lane, wv, cb);
    cell_dense (L, mtg, ctr, p.w[12], p.w[13], p.w[14], p.w[15], tid, lane, wv, cb);
    proj_step(L, ppb, ctr, p.Wp, p.bp,
              p.out + (size_t)t * 4096 + (size_t)batch * 64, tid, part, cb);
  }
}

__global__ void zerob(unsigned* b) { b[blockIdx.x * 256 + threadIdx.x] = 0u; }

extern "C" void kernel_launch(void* const* d_in, const int* in_sizes, int n_in,
                              void* d_out, int out_size, void* d_ws, size_t ws_size,
                              hipStream_t stream)
{
  KP p;
  p.inp = (const float*)d_in[0];
  p.S   = (const float*)d_in[2];
  for (int i = 0; i < 16; ++i) p.w[i] = (const float*)d_in[3 + i];
  p.Wp = (const float*)d_in[19];
  p.bp = (const float*)d_in[20];
  p.out = (float*)d_out;
  float* ws = (float*)d_ws;
  p.mtg = ws;                                   // 64*384*64 floats = 6.29 MB
  p.pp  = ws + (size_t)64 * 384 * 64;           // 64*256 floats
  p.bar = (unsigned*)(p.pp + 64 * 256);         // 64*16 uints

  zerob<<<dim3(4), dim3(256), 0, stream>>>(p.bar);
  (void)hipFuncSetAttribute((const void*)gcgru_coop,
                            hipFuncAttributeMaxDynamicSharedMemorySize, LDS_BYTES);
  void* args[] = { (void*)&p };
  (void)hipLaunchCooperativeKernel((void*)gcgru_coop, dim3(256), dim3(NTH),
                                   args, LDS_BYTES, stream);
}